// Round 13
// baseline (76.032 us; speedup 1.0000x reference)
//
#include <hip/hip_runtime.h>
#include <hip/hip_bf16.h>

#define S_ 2048
#define E_ 1024
#define QNC 16   // qkv K-chunks of 64 f32

typedef __attribute__((ext_vector_type(8))) short short8;
typedef __attribute__((ext_vector_type(4))) float f32x4;

__device__ __forceinline__ short f2bf(float f) {
    __hip_bfloat16 h = __float2bfloat16(f);
    return *(short*)&h;
}

__device__ __forceinline__ void g2l16(const void* g, void* l) {
    __builtin_amdgcn_global_load_lds(
        (const __attribute__((address_space(1))) void*)g,
        (__attribute__((address_space(3))) void*)l, 16, 0, 0);
}

// Wq/Wk/Wv [1024][64] f32 -> Wt bf16 [192 cols][1024 K] (col-major per output).
__global__ __launch_bounds__(256) void prep_weights(
    const float* __restrict__ Wq, const float* __restrict__ Wk,
    const float* __restrict__ Wv, unsigned short* __restrict__ Wt)
{
    int idx = blockIdx.x * 256 + threadIdx.x;  // 192*1024, grid 768
    int n = idx >> 10, k = idx & (E_ - 1);
    const float* W = (n < 64) ? Wq : (n < 128) ? Wk : Wv;
    Wt[idx] = (unsigned short)f2bf(W[k * 64 + (n & 63)]);
}

// QKV v13 — attn_stage ring discipline: 3-buffer LDS ring, depth-2 prefetch,
// counted vmcnt(5) (never blocks on the newest chunk), zero register global
// loads in the loop. Block = 256 thr (4 waves) x 32 rows x 96 cols (col-half);
// grid 1024 = 512 row-groups x 2 col-halves (interleaved: the 2 blocks/CU
// share x rows). Buffer = x 8KB + Wt 12KB = 20KB; 3 ring = 60KB -> 2 blk/CU.
// 16B-unit XOR swizzle both sides -> conflict-free ds_read_b128.
__global__ __launch_bounds__(256, 2) void qkv_main(
    const float* __restrict__ x, const unsigned short* __restrict__ Wt,
    const float* __restrict__ bq, const float* __restrict__ bk,
    const float* __restrict__ bv,
    unsigned short* __restrict__ Q, unsigned short* __restrict__ K,
    unsigned short* __restrict__ Vt)
{
    __shared__ __align__(16) char pool[3][20480];   // [x 8KB | Wt 12KB] x3
    int tid = threadIdx.x;
    int wave = tid >> 6, lane = tid & 63;
    int lo = lane & 15, hi = lane >> 4;
    int wm = wave >> 1, wn = wave & 1;     // 16-row half, 48-col half
    int rb = blockIdx.x >> 1, ch = blockIdx.x & 1;
    int rowbase = rb * 32;
    int colbase = ch * 96;
    const char* xg = (const char*)x;
    const char* wg = (const char*)Wt;

    f32x4 acc[3];
    #pragma unroll
    for (int j = 0; j < 3; ++j) acc[j] = (f32x4){0.f, 0.f, 0.f, 0.f};

    // chunk kc: x = 32 rows x 256B (512 units, 2/thr), Wt = 96 cols x 128B
    // (768 units, 3/thr). 5 DMA/thread, wave-uniform dst, pre-swizzled src.
    #define STAGE(bb, kc)                                                         \
        {                                                                         \
            _Pragma("unroll")                                                     \
            for (int i = 0; i < 2; ++i) {                                         \
                int u_lin = i * 256 + tid;                                        \
                int r = u_lin >> 4, u = u_lin & 15;                               \
                const char* src = xg + (size_t)(rowbase + r) * 4096 + (kc) * 256  \
                                  + (((u & 8) | ((u & 7) ^ (r & 7))) << 4);       \
                g2l16(src, &pool[bb][(i * 256 + wave * 64) * 16]);                \
            }                                                                     \
            _Pragma("unroll")                                                     \
            for (int i = 0; i < 3; ++i) {                                         \
                int u_lin = i * 256 + tid;                                        \
                int cl = u_lin >> 3, u = u_lin & 7;                               \
                const char* src = wg + (size_t)(colbase + cl) * 2048 + (kc) * 128 \
                                  + ((u ^ (cl & 7)) << 4);                        \
                g2l16(src, &pool[bb][8192 + (i * 256 + wave * 64) * 16]);         \
            }                                                                     \
        }

    STAGE(0, 0); STAGE(1, 1);                          // 10 outstanding
    asm volatile("s_waitcnt vmcnt(5)" ::: "memory");   // chunk 0 retired
    __builtin_amdgcn_sched_barrier(0);
    __builtin_amdgcn_s_barrier();

    for (int t = 0; t < QNC; ++t) {
        if (t + 2 < QNC) STAGE((t + 2) % 3, t + 2);    // issue-early, depth-2

        const char* lx = pool[t % 3];
        const char* lw = pool[t % 3] + 8192;
        int r = wm * 16 + lo;
        #pragma unroll
        for (int kk = 0; kk < 2; ++kk) {
            int u0 = kk * 8 + hi * 2;
            float4 a0 = *(const float4*)(lx + r * 256
                + (((u0 & 8) | ((u0 & 7) ^ (r & 7))) << 4));
            float4 a1 = *(const float4*)(lx + r * 256
                + ((((u0 + 1) & 8) | (((u0 + 1) & 7) ^ (r & 7))) << 4));
            short8 af;
            af[0] = f2bf(a0.x); af[1] = f2bf(a0.y);
            af[2] = f2bf(a0.z); af[3] = f2bf(a0.w);
            af[4] = f2bf(a1.x); af[5] = f2bf(a1.y);
            af[6] = f2bf(a1.z); af[7] = f2bf(a1.w);
            #pragma unroll
            for (int j = 0; j < 3; ++j) {
                int cl = wn * 48 + j * 16 + lo;
                short8 bf = *(const short8*)(lw + cl * 128
                    + (((kk * 4 + hi) ^ (cl & 7)) << 4));
                acc[j] = __builtin_amdgcn_mfma_f32_16x16x32_bf16(af, bf, acc[j], 0, 0, 0);
            }
        }

        __builtin_amdgcn_sched_barrier(0);
        if (t + 2 < QNC)      asm volatile("s_waitcnt vmcnt(5)" ::: "memory");
        else if (t + 1 < QNC) asm volatile("s_waitcnt vmcnt(0)" ::: "memory");
        if (t + 1 < QNC) {
            __builtin_amdgcn_sched_barrier(0);
            __builtin_amdgcn_s_barrier();
        }
    }
    #undef STAGE

    // ---- coalesced epilogue: bias -> LDS tiles (alias ring) -> 16B stores ----
    __syncthreads();
    char* eq = pool[0];                             // [32 rows][208B] (96 cols)
    unsigned short* ev = (unsigned short*)pool[1];  // [64 h][40 shorts]
    #pragma unroll
    for (int j = 0; j < 3; ++j) {
        int nl = wn * 48 + j * 16 + lo;             // local col 0..95
        int n = colbase + nl;
        #pragma unroll
        for (int r4 = 0; r4 < 4; ++r4) {
            int rr = wm * 16 + 4 * hi + r4;         // local row 0..31
            float v = acc[j][r4];
            if (n < 64) {
                *(unsigned short*)(eq + rr * 208 + nl * 2) =
                    (unsigned short)f2bf(v + bq[n]);
            } else if (n < 128) {
                *(unsigned short*)(eq + rr * 208 + nl * 2) =
                    (unsigned short)f2bf(v + bk[n - 64]);
            } else {
                ev[(n - 128) * 40 + rr] = (unsigned short)f2bf(v + bv[n - 128]);
            }
        }
    }
    __syncthreads();

    if (ch == 0) {
        // Q: 32 rows x 8 units (1/thread); K cols 0..31: 32 rows x 4 units
        {
            int row = tid >> 3, seg = tid & 7;
            short8 val = *(const short8*)(eq + row * 208 + seg * 16);
            *(short8*)(Q + (size_t)(rowbase + row) * 64 + seg * 8) = val;
        }
        if (tid < 128) {
            int row = tid >> 2, seg = tid & 3;
            short8 val = *(const short8*)(eq + row * 208 + 128 + seg * 16);
            *(short8*)(K + (size_t)(rowbase + row) * 64 + seg * 8) = val;
        }
    } else {
        // K cols 32..63: 32 rows x 4 units
        if (tid < 128) {
            int row = tid >> 2, seg = tid & 3;
            short8 val = *(const short8*)(eq + row * 208 + seg * 16);
            *(short8*)(K + (size_t)(rowbase + row) * 64 + 32 + seg * 8) = val;
        }
        // Vt: 64 h x 4 units (8 s each), 1/thread
        {
            int h = tid >> 2, su = tid & 3;
            int b = rowbase >> 11, sl0 = rowbase & (S_ - 1);
            short8 val = *(const short8*)(ev + h * 40 + su * 8);
            *(short8*)(Vt + ((size_t)(b * 64 + h)) * S_ + sl0 + su * 8) = val;
        }
    }
}

// Flash attention, no-max softmax (unchanged): 3-buffer LDS ring, depth-2
// prefetch, one raw s_barrier per tile with counted vmcnt, masks pre-folded.
__global__ __launch_bounds__(256) void attn_stage(
    const unsigned short* __restrict__ Q, const unsigned short* __restrict__ K,
    const unsigned short* __restrict__ Vt, const int* __restrict__ mask,
    float* __restrict__ part)
{
    __shared__ __align__(16) char kv[3][16384];            // [K 8KB | V 8KB] x3
    __shared__ __align__(16) unsigned short p_lds[4][16][72];
    int tid = threadIdx.x;
    int wave = tid >> 6, lane = tid & 63;
    int lo = lane & 15, hi = lane >> 4;
    int blk = blockIdx.x;
    int c = blk & 3;
    int pr = blk >> 2;
    int b = pr & 7;
    int qt64 = 31 - (pr >> 3);          // heavy first
    int nkt = qt64 + 1;
    int chunk = (nkt + 3) >> 2;
    int kt0 = c * chunk;
    int kt1 = min(kt0 + chunk, nkt);
    int ntile = kt1 - kt0;              // <= 8
    int qrow0 = qt64 * 64 + wave * 16;

    f32x4 o[4];
    float ps[4] = {0.f, 0.f, 0.f, 0.f};
    #pragma unroll
    for (int i = 0; i < 4; ++i) o[i] = (f32x4){0.f, 0.f, 0.f, 0.f};

    #define ASTAGE(bb, kt)                                                        \
        {                                                                         \
            int kbase_ = (kt) * 64;                                               \
            const char* kg = (const char*)K + (size_t)(b * S_ + kbase_) * 128;    \
            const char* vg = (const char*)Vt + (size_t)b * 64 * 4096 + kbase_ * 2;\
            _Pragma("unroll")                                                     \
            for (int j = 0; j < 2; ++j) {                                         \
                int r = (j * 4 + wave) * 8 + (lane >> 3);                         \
                int un = lane & 7;                                                \
                g2l16(kg + r * 128 + ((un ^ (r & 7)) << 4),                       \
                      &kv[bb][(j * 4 + wave) * 1024]);                            \
                g2l16(vg + (size_t)r * 4096 + ((un ^ (r & 7)) << 4),              \
                      &kv[bb][8192 + (j * 4 + wave) * 1024]);                     \
            }                                                                     \
        }

    if (ntile > 0) {
        const unsigned short* qp = Q + ((size_t)(b * S_ + qrow0 + lo)) * 64 + 8 * hi;
        short8 qf0 = *(const short8*)(qp);
        short8 qf1 = *(const short8*)(qp + 32);

        unsigned mbits = 0;
        for (int tt = 0; tt < 8; ++tt) {
            if (tt < ntile) {
                int kbase = (kt0 + tt) * 64;
                #pragma unroll
                for (int nt = 0; nt < 4; ++nt)
                    if (mask[b * S_ + kbase + nt * 16 + lo] != 0)
                        mbits |= (1u << (tt * 4 + nt));
            }
        }
        asm volatile("s_waitcnt vmcnt(0)" ::: "memory");
        __builtin_amdgcn_sched_barrier(0);

        ASTAGE(0, kt0);
        if (ntile > 1) ASTAGE(1, kt0 + 1);
        __builtin_amdgcn_sched_barrier(0);
        if (ntile > 1) asm volatile("s_waitcnt vmcnt(4)" ::: "memory");
        else           asm volatile("s_waitcnt vmcnt(0)" ::: "memory");
        __builtin_amdgcn_sched_barrier(0);
        __builtin_amdgcn_s_barrier();

        for (int t = 0; t < ntile; ++t) {
            int kbase = (kt0 + t) * 64;
            const char* kb = kv[t % 3];
            const char* vb = kv[t % 3] + 8192;

            f32x4 s[4];
            #pragma unroll
            for (int i = 0; i < 4; ++i) s[i] = (f32x4){0.f, 0.f, 0.f, 0.f};
            #pragma unroll
            for (int nt = 0; nt < 4; ++nt) {
                short8 kf0 = *(const short8*)(kb + (nt * 16 + lo) * 128 + ((hi ^ (lo & 7)) << 4));
                short8 kf1 = *(const short8*)(kb + (nt * 16 + lo) * 128 + (((4 + hi) ^ (lo & 7)) << 4));
                s[nt] = __builtin_amdgcn_mfma_f32_16x16x32_bf16(qf0, kf0, s[nt], 0, 0, 0);
                s[nt] = __builtin_amdgcn_mfma_f32_16x16x32_bf16(qf1, kf1, s[nt], 0, 0, 0);
            }

            #pragma unroll
            for (int nt = 0; nt < 4; ++nt) {
                int kpos = kbase + nt * 16 + lo;
                bool mok = (mbits >> (t * 4 + nt)) & 1;
                #pragma unroll
                for (int r = 0; r < 4; ++r) {
                    int qpos = qrow0 + 4 * hi + r;
                    bool ok = mok && (kpos <= qpos);
                    float pv = ok ? __expf(s[nt][r] * 0.125f) : 0.f;
                    ps[r] += pv;
                    p_lds[wave][4 * hi + r][nt * 16 + lo] = (unsigned short)f2bf(pv);
                }
            }

            #pragma unroll
            for (int kk = 0; kk < 2; ++kk) {
                short8 pf = *(const short8*)&p_lds[wave][lo][kk * 32 + 8 * hi];
                #pragma unroll
                for (int nt = 0; nt < 4; ++nt) {
                    short8 vf = *(const short8*)(vb + (nt * 16 + lo) * 128
                                                 + (((kk * 4 + hi) ^ (lo & 7)) << 4));
                    o[nt] = __builtin_amdgcn_mfma_f32_16x16x32_bf16(pf, vf, o[nt], 0, 0, 0);
                }
            }

            if (t + 2 < ntile) ASTAGE((t + 2) % 3, kt0 + t + 2);
            __builtin_amdgcn_sched_barrier(0);
            if (t + 1 < ntile) {
                if (t + 2 < ntile) asm volatile("s_waitcnt vmcnt(4)" ::: "memory");
                else               asm volatile("s_waitcnt vmcnt(0)" ::: "memory");
                __builtin_amdgcn_sched_barrier(0);
                __builtin_amdgcn_s_barrier();
            }
        }
    }
    #undef ASTAGE

    float l[4];
    #pragma unroll
    for (int r = 0; r < 4; ++r) {
        float v = ps[r];
        v += __shfl_xor(v, 1);
        v += __shfl_xor(v, 2);
        v += __shfl_xor(v, 4);
        v += __shfl_xor(v, 8);
        l[r] = v;
    }

    int tile16 = b * 128 + qt64 * 4 + wave;
    float* pp = part + (((size_t)c * 1024 + tile16) * 64 + lane) * 20;
    #pragma unroll
    for (int nt = 0; nt < 4; ++nt) *(f32x4*)(pp + nt * 4) = o[nt];
    f32x4 ll;
    #pragma unroll
    for (int r = 0; r < 4; ++r) ll[r] = l[r];
    *(f32x4*)(pp + 16) = ll;
}

// Sum 4 kv-chunk partials (additive) and normalize.
__global__ __launch_bounds__(256) void attn_comb(
    const float* __restrict__ part, float* __restrict__ out)
{
    int g = blockIdx.x * 256 + threadIdx.x;   // 65536
    int tile = g >> 6, lane = g & 63;
    int lo = lane & 15, hi = lane >> 4;
    int b = tile >> 7, qt = tile & 127;
    int qrow0 = qt * 16;

    f32x4 o[4];
    float l[4] = {0.f, 0.f, 0.f, 0.f};
    #pragma unroll
    for (int i = 0; i < 4; ++i) o[i] = (f32x4){0.f, 0.f, 0.f, 0.f};

    #pragma unroll
    for (int c = 0; c < 4; ++c) {
        const float* pp = part + (((size_t)c * 1024 + tile) * 64 + lane) * 20;
        #pragma unroll
        for (int nt = 0; nt < 4; ++nt) {
            f32x4 po = *(const f32x4*)(pp + nt * 4);
            #pragma unroll
            for (int r = 0; r < 4; ++r) o[nt][r] += po[r];
        }
        f32x4 pl = *(const f32x4*)(pp + 16);
        #pragma unroll
        for (int r = 0; r < 4; ++r) l[r] += pl[r];
    }

    #pragma unroll
    for (int nt = 0; nt < 4; ++nt) {
        #pragma unroll
        for (int r = 0; r < 4; ++r) {
            int qpos = qrow0 + 4 * hi + r;
            out[((size_t)(b * S_ + qpos)) * 64 + nt * 16 + lo] =
                (l[r] > 0.f) ? o[nt][r] / l[r] : 0.f;
        }
    }
}

extern "C" void kernel_launch(void* const* d_in, const int* in_sizes, int n_in,
                              void* d_out, int out_size, void* d_ws, size_t ws_size,
                              hipStream_t stream) {
    const float* x   = (const float*)d_in[0];
    const int*   msk = (const int*)d_in[1];
    const float* Wq  = (const float*)d_in[2];
    const float* bq  = (const float*)d_in[3];
    const float* Wk  = (const float*)d_in[4];
    const float* bk  = (const float*)d_in[5];
    const float* Wv  = (const float*)d_in[6];
    const float* bv  = (const float*)d_in[7];
    float* outp = (float*)d_out;

    // ws layout: Wt @0 (384KB, pad 512KB) | Q @0x080000 | K @0x280000
    //            Vt @0x480000 | part @0x680000 (4*1024*64*20 f32 = 21 MB)
    char* w = (char*)d_ws;
    unsigned short* Wt = (unsigned short*)w;
    unsigned short* Qb = (unsigned short*)(w + 0x080000);
    unsigned short* Kb = (unsigned short*)(w + 0x280000);
    unsigned short* Vt = (unsigned short*)(w + 0x480000);
    float* partp = (float*)(w + 0x680000);

    prep_weights<<<dim3(768), dim3(256), 0, stream>>>(Wq, Wk, Wv, Wt);
    qkv_main<<<dim3(1024), dim3(256), 0, stream>>>(x, Wt, bq, bk, bv, Qb, Kb, Vt);
    attn_stage<<<dim3(1024), dim3(256), 0, stream>>>(Qb, Kb, Vt, msk, partp);
    attn_comb<<<dim3(256), dim3(256), 0, stream>>>(partp, outp);
}

// Round 14
// 65.830 us; speedup vs baseline: 1.1550x; 1.1550x over previous
//
#include <hip/hip_runtime.h>
#include <hip/hip_bf16.h>

#define S_ 2048
#define E_ 1024
#define QNC 16   // qkv K-chunks of 64 f32

typedef __attribute__((ext_vector_type(8))) short short8;
typedef __attribute__((ext_vector_type(4))) float f32x4;

__device__ __forceinline__ short f2bf(float f) {
    __hip_bfloat16 h = __float2bfloat16(f);
    return *(short*)&h;
}

__device__ __forceinline__ void g2l16(const void* g, void* l) {
    __builtin_amdgcn_global_load_lds(
        (const __attribute__((address_space(1))) void*)g,
        (__attribute__((address_space(3))) void*)l, 16, 0, 0);
}

// Wq/Wk/Wv [1024][64] f32 -> Wt bf16 [192 cols][1024 K] (col-major per output).
__global__ __launch_bounds__(256) void prep_weights(
    const float* __restrict__ Wq, const float* __restrict__ Wk,
    const float* __restrict__ Wv, unsigned short* __restrict__ Wt)
{
    int idx = blockIdx.x * 256 + threadIdx.x;  // 192*1024, grid 768
    int n = idx >> 10, k = idx & (E_ - 1);
    const float* W = (n < 64) ? Wq : (n < 128) ? Wk : Wv;
    Wt[idx] = (unsigned short)f2bf(W[k * 64 + (n & 63)]);
}

// QKV v14 — minimize staged bytes + maximize in-flight DMA.
// M=64/block, 256 blocks (1/CU) x 256 thr (4 waves: wm=32-row half, wn=96-col
// half). K-chunk 64 f32: buffer = x 16KB + Wt 24KB = 40KB; 3-ring = 120KB LDS.
// Depth-2 prefetch, 10 DMA/thread/chunk, steady wait vmcnt(10) -> 40KB/CU in
// flight. Total staged = x 64MB + Wt 96MB = 160MB (vs 262MB in v12).
// 16B-unit XOR swizzle both sides -> conflict-free (<=2-way) ds_read_b128.
__global__ __launch_bounds__(256, 1) void qkv_main(
    const float* __restrict__ x, const unsigned short* __restrict__ Wt,
    const float* __restrict__ bq, const float* __restrict__ bk,
    const float* __restrict__ bv,
    unsigned short* __restrict__ Q, unsigned short* __restrict__ K,
    unsigned short* __restrict__ Vt)
{
    __shared__ __align__(16) char pool[3][40960];   // [x 16KB | Wt 24KB] x3
    int tid = threadIdx.x;
    int wave = tid >> 6, lane = tid & 63;
    int lo = lane & 15, hi = lane >> 4;
    int wm = wave >> 1, wn = wave & 1;     // 32-row half, 96-col half
    int rowbase = blockIdx.x * 64;
    const char* xg = (const char*)x;
    const char* wg = (const char*)Wt;

    f32x4 acc[2][6];
    #pragma unroll
    for (int a = 0; a < 2; ++a)
        #pragma unroll
        for (int j = 0; j < 6; ++j) acc[a][j] = (f32x4){0.f, 0.f, 0.f, 0.f};

    // chunk kc: x = 64 rows x 256B (1024 units, 4/thr), Wt = 192 cols x 128B
    // (1536 units, 6/thr). 10 DMA/thread, wave-uniform dst, pre-swizzled src.
    #define STAGE(bb, kc)                                                         \
        {                                                                         \
            _Pragma("unroll")                                                     \
            for (int i = 0; i < 4; ++i) {                                         \
                int u_lin = i * 256 + tid;                                        \
                int r = u_lin >> 4, u = u_lin & 15;                               \
                const char* src = xg + (size_t)(rowbase + r) * 4096 + (kc) * 256  \
                                  + (((u & 8) | ((u & 7) ^ (r & 7))) << 4);       \
                g2l16(src, &pool[bb][(i * 256 + wave * 64) * 16]);                \
            }                                                                     \
            _Pragma("unroll")                                                     \
            for (int i = 0; i < 6; ++i) {                                         \
                int u_lin = i * 256 + tid;                                        \
                int cl = u_lin >> 3, u = u_lin & 7;                               \
                const char* src = wg + (size_t)cl * 2048 + (kc) * 128             \
                                  + ((u ^ (cl & 7)) << 4);                        \
                g2l16(src, &pool[bb][16384 + (i * 256 + wave * 64) * 16]);        \
            }                                                                     \
        }

    STAGE(0, 0); STAGE(1, 1);                          // 20 outstanding
    asm volatile("s_waitcnt vmcnt(10)" ::: "memory");  // chunk 0 retired
    __builtin_amdgcn_sched_barrier(0);
    __builtin_amdgcn_s_barrier();

    for (int t = 0; t < QNC; ++t) {
        if (t + 2 < QNC) STAGE((t + 2) % 3, t + 2);    // issue-early, depth-2

        const char* lx = pool[t % 3];
        const char* lw = pool[t % 3] + 16384;
        #pragma unroll
        for (int kk = 0; kk < 2; ++kk) {
            // 6 B-fragments for this kk (shared by both row-halves)
            short8 bf[6];
            #pragma unroll
            for (int j = 0; j < 6; ++j) {
                int cl = wn * 96 + j * 16 + lo;
                bf[j] = *(const short8*)(lw + cl * 128
                    + (((kk * 4 + hi) ^ (cl & 7)) << 4));
            }
            #pragma unroll
            for (int rt = 0; rt < 2; ++rt) {
                int r = wm * 32 + rt * 16 + lo;
                int u0 = kk * 8 + hi * 2;
                float4 a0 = *(const float4*)(lx + r * 256
                    + (((u0 & 8) | ((u0 & 7) ^ (r & 7))) << 4));
                float4 a1 = *(const float4*)(lx + r * 256
                    + ((((u0 + 1) & 8) | (((u0 + 1) & 7) ^ (r & 7))) << 4));
                short8 af;
                af[0] = f2bf(a0.x); af[1] = f2bf(a0.y);
                af[2] = f2bf(a0.z); af[3] = f2bf(a0.w);
                af[4] = f2bf(a1.x); af[5] = f2bf(a1.y);
                af[6] = f2bf(a1.z); af[7] = f2bf(a1.w);
                #pragma unroll
                for (int j = 0; j < 6; ++j)
                    acc[rt][j] = __builtin_amdgcn_mfma_f32_16x16x32_bf16(
                        af, bf[j], acc[rt][j], 0, 0, 0);
            }
        }

        __builtin_amdgcn_sched_barrier(0);
        if (t + 2 < QNC)      asm volatile("s_waitcnt vmcnt(10)" ::: "memory");
        else if (t + 1 < QNC) asm volatile("s_waitcnt vmcnt(0)" ::: "memory");
        if (t + 1 < QNC) {
            __builtin_amdgcn_sched_barrier(0);
            __builtin_amdgcn_s_barrier();
        }
    }
    #undef STAGE

    // ---- coalesced epilogue: bias -> LDS tiles (alias ring) -> 16B stores ----
    __syncthreads();
    char* eq = pool[0];                             // [64 rows][272B] = 17.4KB
    unsigned short* ev = (unsigned short*)pool[2];  // [64 h][72 shorts] = 9.2KB
    #pragma unroll
    for (int rt = 0; rt < 2; ++rt) {
        #pragma unroll
        for (int j = 0; j < 6; ++j) {
            int n = wn * 96 + j * 16 + lo;
            #pragma unroll
            for (int r4 = 0; r4 < 4; ++r4) {
                int rr = wm * 32 + rt * 16 + 4 * hi + r4;   // local row 0..63
                float v = acc[rt][j][r4];
                if (n < 64) {
                    *(unsigned short*)(eq + rr * 272 + n * 2) =
                        (unsigned short)f2bf(v + bq[n]);
                } else if (n < 128) {
                    *(unsigned short*)(eq + rr * 272 + n * 2) =
                        (unsigned short)f2bf(v + bk[n - 64]);
                } else {
                    ev[(n - 128) * 72 + rr] = (unsigned short)f2bf(v + bv[n - 128]);
                }
            }
        }
    }
    __syncthreads();

    {
        // Q/K: 64 rows x 16 units (Q 0-7, K 8-15), 4/thread
        #pragma unroll
        for (int i = 0; i < 4; ++i) {
            int u_lin = i * 256 + tid;
            int row = u_lin >> 4, seg = u_lin & 15;
            short8 val = *(const short8*)(eq + row * 272 + seg * 16);
            if (seg < 8)
                *(short8*)(Q + (size_t)(rowbase + row) * 64 + seg * 8) = val;
            else
                *(short8*)(K + (size_t)(rowbase + row) * 64 + (seg - 8) * 8) = val;
        }
        // Vt: 64 h x 8 units (8 s each), 2/thread
        int b = rowbase >> 11, sl0 = rowbase & (S_ - 1);
        #pragma unroll
        for (int i = 0; i < 2; ++i) {
            int u_lin = i * 256 + tid;
            int h = u_lin >> 3, su = u_lin & 7;
            short8 val = *(const short8*)(ev + h * 72 + su * 8);
            *(short8*)(Vt + ((size_t)(b * 64 + h)) * S_ + sl0 + su * 8) = val;
        }
    }
}

// Flash attention, no-max softmax (unchanged): 3-buffer LDS ring, depth-2
// prefetch, one raw s_barrier per tile with counted vmcnt, masks pre-folded.
__global__ __launch_bounds__(256) void attn_stage(
    const unsigned short* __restrict__ Q, const unsigned short* __restrict__ K,
    const unsigned short* __restrict__ Vt, const int* __restrict__ mask,
    float* __restrict__ part)
{
    __shared__ __align__(16) char kv[3][16384];            // [K 8KB | V 8KB] x3
    __shared__ __align__(16) unsigned short p_lds[4][16][72];
    int tid = threadIdx.x;
    int wave = tid >> 6, lane = tid & 63;
    int lo = lane & 15, hi = lane >> 4;
    int blk = blockIdx.x;
    int c = blk & 3;
    int pr = blk >> 2;
    int b = pr & 7;
    int qt64 = 31 - (pr >> 3);          // heavy first
    int nkt = qt64 + 1;
    int chunk = (nkt + 3) >> 2;
    int kt0 = c * chunk;
    int kt1 = min(kt0 + chunk, nkt);
    int ntile = kt1 - kt0;              // <= 8
    int qrow0 = qt64 * 64 + wave * 16;

    f32x4 o[4];
    float ps[4] = {0.f, 0.f, 0.f, 0.f};
    #pragma unroll
    for (int i = 0; i < 4; ++i) o[i] = (f32x4){0.f, 0.f, 0.f, 0.f};

    #define ASTAGE(bb, kt)                                                        \
        {                                                                         \
            int kbase_ = (kt) * 64;                                               \
            const char* kg = (const char*)K + (size_t)(b * S_ + kbase_) * 128;    \
            const char* vg = (const char*)Vt + (size_t)b * 64 * 4096 + kbase_ * 2;\
            _Pragma("unroll")                                                     \
            for (int j = 0; j < 2; ++j) {                                         \
                int r = (j * 4 + wave) * 8 + (lane >> 3);                         \
                int un = lane & 7;                                                \
                g2l16(kg + r * 128 + ((un ^ (r & 7)) << 4),                       \
                      &kv[bb][(j * 4 + wave) * 1024]);                            \
                g2l16(vg + (size_t)r * 4096 + ((un ^ (r & 7)) << 4),              \
                      &kv[bb][8192 + (j * 4 + wave) * 1024]);                     \
            }                                                                     \
        }

    if (ntile > 0) {
        const unsigned short* qp = Q + ((size_t)(b * S_ + qrow0 + lo)) * 64 + 8 * hi;
        short8 qf0 = *(const short8*)(qp);
        short8 qf1 = *(const short8*)(qp + 32);

        unsigned mbits = 0;
        for (int tt = 0; tt < 8; ++tt) {
            if (tt < ntile) {
                int kbase = (kt0 + tt) * 64;
                #pragma unroll
                for (int nt = 0; nt < 4; ++nt)
                    if (mask[b * S_ + kbase + nt * 16 + lo] != 0)
                        mbits |= (1u << (tt * 4 + nt));
            }
        }
        asm volatile("s_waitcnt vmcnt(0)" ::: "memory");
        __builtin_amdgcn_sched_barrier(0);

        ASTAGE(0, kt0);
        if (ntile > 1) ASTAGE(1, kt0 + 1);
        __builtin_amdgcn_sched_barrier(0);
        if (ntile > 1) asm volatile("s_waitcnt vmcnt(4)" ::: "memory");
        else           asm volatile("s_waitcnt vmcnt(0)" ::: "memory");
        __builtin_amdgcn_sched_barrier(0);
        __builtin_amdgcn_s_barrier();

        for (int t = 0; t < ntile; ++t) {
            int kbase = (kt0 + t) * 64;
            const char* kb = kv[t % 3];
            const char* vb = kv[t % 3] + 8192;

            f32x4 s[4];
            #pragma unroll
            for (int i = 0; i < 4; ++i) s[i] = (f32x4){0.f, 0.f, 0.f, 0.f};
            #pragma unroll
            for (int nt = 0; nt < 4; ++nt) {
                short8 kf0 = *(const short8*)(kb + (nt * 16 + lo) * 128 + ((hi ^ (lo & 7)) << 4));
                short8 kf1 = *(const short8*)(kb + (nt * 16 + lo) * 128 + (((4 + hi) ^ (lo & 7)) << 4));
                s[nt] = __builtin_amdgcn_mfma_f32_16x16x32_bf16(qf0, kf0, s[nt], 0, 0, 0);
                s[nt] = __builtin_amdgcn_mfma_f32_16x16x32_bf16(qf1, kf1, s[nt], 0, 0, 0);
            }

            #pragma unroll
            for (int nt = 0; nt < 4; ++nt) {
                int kpos = kbase + nt * 16 + lo;
                bool mok = (mbits >> (t * 4 + nt)) & 1;
                #pragma unroll
                for (int r = 0; r < 4; ++r) {
                    int qpos = qrow0 + 4 * hi + r;
                    bool ok = mok && (kpos <= qpos);
                    float pv = ok ? __expf(s[nt][r] * 0.125f) : 0.f;
                    ps[r] += pv;
                    p_lds[wave][4 * hi + r][nt * 16 + lo] = (unsigned short)f2bf(pv);
                }
            }

            #pragma unroll
            for (int kk = 0; kk < 2; ++kk) {
                short8 pf = *(const short8*)&p_lds[wave][lo][kk * 32 + 8 * hi];
                #pragma unroll
                for (int nt = 0; nt < 4; ++nt) {
                    short8 vf = *(const short8*)(vb + (nt * 16 + lo) * 128
                                                 + (((kk * 4 + hi) ^ (lo & 7)) << 4));
                    o[nt] = __builtin_amdgcn_mfma_f32_16x16x32_bf16(pf, vf, o[nt], 0, 0, 0);
                }
            }

            if (t + 2 < ntile) ASTAGE((t + 2) % 3, kt0 + t + 2);
            __builtin_amdgcn_sched_barrier(0);
            if (t + 1 < ntile) {
                if (t + 2 < ntile) asm volatile("s_waitcnt vmcnt(4)" ::: "memory");
                else               asm volatile("s_waitcnt vmcnt(0)" ::: "memory");
                __builtin_amdgcn_sched_barrier(0);
                __builtin_amdgcn_s_barrier();
            }
        }
    }
    #undef ASTAGE

    float l[4];
    #pragma unroll
    for (int r = 0; r < 4; ++r) {
        float v = ps[r];
        v += __shfl_xor(v, 1);
        v += __shfl_xor(v, 2);
        v += __shfl_xor(v, 4);
        v += __shfl_xor(v, 8);
        l[r] = v;
    }

    int tile16 = b * 128 + qt64 * 4 + wave;
    float* pp = part + (((size_t)c * 1024 + tile16) * 64 + lane) * 20;
    #pragma unroll
    for (int nt = 0; nt < 4; ++nt) *(f32x4*)(pp + nt * 4) = o[nt];
    f32x4 ll;
    #pragma unroll
    for (int r = 0; r < 4; ++r) ll[r] = l[r];
    *(f32x4*)(pp + 16) = ll;
}

// Sum 4 kv-chunk partials (additive) and normalize.
__global__ __launch_bounds__(256) void attn_comb(
    const float* __restrict__ part, float* __restrict__ out)
{
    int g = blockIdx.x * 256 + threadIdx.x;   // 65536
    int tile = g >> 6, lane = g & 63;
    int lo = lane & 15, hi = lane >> 4;
    int b = tile >> 7, qt = tile & 127;
    int qrow0 = qt * 16;

    f32x4 o[4];
    float l[4] = {0.f, 0.f, 0.f, 0.f};
    #pragma unroll
    for (int i = 0; i < 4; ++i) o[i] = (f32x4){0.f, 0.f, 0.f, 0.f};

    #pragma unroll
    for (int c = 0; c < 4; ++c) {
        const float* pp = part + (((size_t)c * 1024 + tile) * 64 + lane) * 20;
        #pragma unroll
        for (int nt = 0; nt < 4; ++nt) {
            f32x4 po = *(const f32x4*)(pp + nt * 4);
            #pragma unroll
            for (int r = 0; r < 4; ++r) o[nt][r] += po[r];
        }
        f32x4 pl = *(const f32x4*)(pp + 16);
        #pragma unroll
        for (int r = 0; r < 4; ++r) l[r] += pl[r];
    }

    #pragma unroll
    for (int nt = 0; nt < 4; ++nt) {
        #pragma unroll
        for (int r = 0; r < 4; ++r) {
            int qpos = qrow0 + 4 * hi + r;
            out[((size_t)(b * S_ + qpos)) * 64 + nt * 16 + lo] =
                (l[r] > 0.f) ? o[nt][r] / l[r] : 0.f;
        }
    }
}

extern "C" void kernel_launch(void* const* d_in, const int* in_sizes, int n_in,
                              void* d_out, int out_size, void* d_ws, size_t ws_size,
                              hipStream_t stream) {
    const float* x   = (const float*)d_in[0];
    const int*   msk = (const int*)d_in[1];
    const float* Wq  = (const float*)d_in[2];
    const float* bq  = (const float*)d_in[3];
    const float* Wk  = (const float*)d_in[4];
    const float* bk  = (const float*)d_in[5];
    const float* Wv  = (const float*)d_in[6];
    const float* bv  = (const float*)d_in[7];
    float* outp = (float*)d_out;

    // ws layout: Wt @0 (384KB, pad 512KB) | Q @0x080000 | K @0x280000
    //            Vt @0x480000 | part @0x680000 (4*1024*64*20 f32 = 21 MB)
    char* w = (char*)d_ws;
    unsigned short* Wt = (unsigned short*)w;
    unsigned short* Qb = (unsigned short*)(w + 0x080000);
    unsigned short* Kb = (unsigned short*)(w + 0x280000);
    unsigned short* Vt = (unsigned short*)(w + 0x480000);
    float* partp = (float*)(w + 0x680000);

    prep_weights<<<dim3(768), dim3(256), 0, stream>>>(Wq, Wk, Wv, Wt);
    qkv_main<<<dim3(256), dim3(256), 0, stream>>>(x, Wt, bq, bk, bv, Qb, Kb, Vt);
    attn_stage<<<dim3(1024), dim3(256), 0, stream>>>(Qb, Kb, Vt, msk, partp);
    attn_comb<<<dim3(256), dim3(256), 0, stream>>>(partp, outp);
}